// Round 1
// 466.644 us; speedup vs baseline: 1.0063x; 1.0063x over previous
//
#include <hip/hip_runtime.h>
#include <math.h>

// IFFTv3: y = IFFT_1024(x) per row, via 8x decimated IDFT_128 (bf16 MFMA GEMM)
// + 8-point inverse-DFT recombination epilogue.
//
// vs v2 (469 us): TB 16->8 (512 thr, 34 KB LDS -> 2 blocks/CU), W pre-converted
// to bf16 in d_ws by a setup kernel and read as MFMA B-fragments directly from
// L2-resident global (no W LDS plane, no per-block reconversion), twiddle LDS
// table replaced by sincos+recurrence in registers (removes 8/16-way bank
// conflicts), epilogue Y reads widened to b64, 1/8 scale folded into W (exact).
//
// inputs: d_in[0]=re (B*1024 f32), d_in[1]=im, d_in[2..5]=wr_u,wr_l,wi_u,wi_l (128*128 f32)
// output: d_out = concat(yr (B*1024 f32), yi (B*1024 f32))
// d_ws: 64 KB = Wr_bf16[128*128] | Wi_bf16[128*128], scale 1/8 folded in

#define BATCH_N   32768
#define NFFT      1024
#define TB        8                  // batch rows per block
#define NTHREADS  512
#define GRID_N    (BATCH_N / TB)     // 4096 blocks

typedef __attribute__((ext_vector_type(8))) short  short8;   // 8 bf16 (4 VGPRs)
typedef __attribute__((ext_vector_type(4))) float  floatx4;  // MFMA acc

// ---- LDS layout ---------------------------------------------------------
// A: 2 planes (Are, Aim), each 64 rows x 136 halfwords (pad +8 breaks bank stride)
// Y: union with A. 64 rows x 130 dwords (bf16 re|im pair)
#define A_STRIDE   136
#define A_PLANE    (64 * A_STRIDE)           // halfwords
#define Y_STRIDE   130                       // dwords
#define SMEM_BYTES (2 * A_PLANE * 2)         // 34816 B -> 2+ blocks/CU LDS-wise

__device__ __forceinline__ unsigned short f2bf(float f) {
    unsigned u = __float_as_uint(f);
    u += 0x7fffu + ((u >> 16) & 1u);          // RNE
    return (unsigned short)(u >> 16);
}
__device__ __forceinline__ float bf2f(unsigned v) {
    return __uint_as_float(v << 16);
}
__device__ __forceinline__ short8 negbf(short8 a) {   // flip bf16 sign bits
    union { short8 s; unsigned u[4]; } x;
    x.s = a;
    x.u[0] ^= 0x80008000u; x.u[1] ^= 0x80008000u;
    x.u[2] ^= 0x80008000u; x.u[3] ^= 0x80008000u;
    return x.s;
}

// ---- setup: W bf16 = (w_u + w_l) * 0.125 (recombine scale folded, exact pow2)
__global__ void prep_w(const float* __restrict__ wru, const float* __restrict__ wrl,
                       const float* __restrict__ wiu, const float* __restrict__ wil,
                       unsigned short* __restrict__ wbf)
{
    int e = (blockIdx.x * 256 + threadIdx.x) * 4;   // 0..16383, step 4
    float4 a = *(const float4*)(wru + e);
    float4 b = *(const float4*)(wrl + e);
    ushort4 pk;
    pk.x = f2bf((a.x + b.x) * 0.125f); pk.y = f2bf((a.y + b.y) * 0.125f);
    pk.z = f2bf((a.z + b.z) * 0.125f); pk.w = f2bf((a.w + b.w) * 0.125f);
    *(ushort4*)(wbf + e) = pk;
    a = *(const float4*)(wiu + e);
    b = *(const float4*)(wil + e);
    pk.x = f2bf((a.x + b.x) * 0.125f); pk.y = f2bf((a.y + b.y) * 0.125f);
    pk.z = f2bf((a.z + b.z) * 0.125f); pk.w = f2bf((a.w + b.w) * 0.125f);
    *(ushort4*)(wbf + 16384 + e) = pk;
}

__global__ __launch_bounds__(NTHREADS, 4)   // VGPR<=128 -> 2 blocks/CU resident
void ifft_fused(const float* __restrict__ re, const float* __restrict__ im,
                const unsigned short* __restrict__ wbf,
                float* __restrict__ out)
{
    __shared__ __align__(16) char smem[SMEM_BYTES];
    unsigned short* Ar = (unsigned short*)smem;
    unsigned short* Ai = Ar + A_PLANE;
    unsigned*       Y  = (unsigned*)smem;     // union with A

    const int t   = threadIdx.x;
    const int blk = blockIdx.x;

    // ---- stage A: de-interleave x[b][8n+r] -> A[b*8+r][n] as bf16 ----
#pragma unroll
    for (int i = 0; i < 8; ++i) {
        int e    = (t + NTHREADS * i) * 4;    // 0..16383, step 4
        int isIm = (e >= TB * NFFT);
        int er   = e & (TB * NFFT - 1);
        int b    = er >> 10;
        int p    = er & 1023;
        const float* src = isIm ? im : re;
        float4 v = *(const float4*)(src + (size_t)(blk * TB + b) * NFFT + p);
        unsigned short* plane = isIm ? Ai : Ar;
        int r0 = p & 7, col = p >> 3;         // p%4==0 -> r0 in {0,4}, same col for 4 elems
        int base = (b * 8 + r0) * A_STRIDE + col;
        plane[base + 0 * A_STRIDE] = f2bf(v.x);
        plane[base + 1 * A_STRIDE] = f2bf(v.y);
        plane[base + 2 * A_STRIDE] = f2bf(v.z);
        plane[base + 3 * A_STRIDE] = f2bf(v.w);
    }
    __syncthreads();

    // ---- GEMM: Y[M=64][N=128] complex = A[M][K=128] * W[K][N] ----
    // 8 waves: 2 (M) x 4 (N), each wave 2 m-tiles x 2 n-tiles of 16x16.
    // W symmetric: B[k][n] = W[n][k] row read, straight from L2-resident global.
    const int w    = t >> 6;
    const int lane = t & 63;
    const int wm   = w & 1;
    const int wn   = w >> 1;
    const int l15  = lane & 15, quad = lane >> 4;
    const unsigned short* Wrg = wbf;
    const unsigned short* Wig = wbf + 16384;

    floatx4 accr[2][2] = {};
    floatx4 acci[2][2] = {};

#pragma unroll
    for (int ks = 0; ks < 4; ++ks) {
        const int kk = ks * 32 + quad * 8;
        short8 arf[2], aif[2], ainf[2], wrf[2], wif[2];
#pragma unroll
        for (int tm = 0; tm < 2; ++tm) {
            int row = (wm * 2 + tm) * 16 + l15;
            arf[tm]  = *(const short8*)(Ar + row * A_STRIDE + kk);
            aif[tm]  = *(const short8*)(Ai + row * A_STRIDE + kk);
            ainf[tm] = negbf(aif[tm]);
        }
#pragma unroll
        for (int tn = 0; tn < 2; ++tn) {
            int rowW = (wn * 2 + tn) * 16 + l15;
            // lanes (quad,l15): row stride 256B, quad covers 64B contiguous -> 16 dense lines
            wrf[tn] = *(const short8*)(Wrg + rowW * 128 + kk);
            wif[tn] = *(const short8*)(Wig + rowW * 128 + kk);
        }
#pragma unroll
        for (int tm = 0; tm < 2; ++tm)
#pragma unroll
            for (int tn = 0; tn < 2; ++tn) {
                accr[tm][tn] = __builtin_amdgcn_mfma_f32_16x16x32_bf16(arf[tm],  wrf[tn], accr[tm][tn], 0, 0, 0);
                accr[tm][tn] = __builtin_amdgcn_mfma_f32_16x16x32_bf16(ainf[tm], wif[tn], accr[tm][tn], 0, 0, 0);
                acci[tm][tn] = __builtin_amdgcn_mfma_f32_16x16x32_bf16(arf[tm],  wif[tn], acci[tm][tn], 0, 0, 0);
                acci[tm][tn] = __builtin_amdgcn_mfma_f32_16x16x32_bf16(aif[tm],  wrf[tn], acci[tm][tn], 0, 0, 0);
            }
    }

    __syncthreads();    // A reads done; Y overwrites the A region

    // ---- dump acc -> Y (packed bf16 re|im<<16). C-layout: col=lane&15, row=quad*4+reg
#pragma unroll
    for (int tm = 0; tm < 2; ++tm)
#pragma unroll
        for (int tn = 0; tn < 2; ++tn)
#pragma unroll
            for (int rg = 0; rg < 4; ++rg) {
                int row = (wm * 2 + tm) * 16 + quad * 4 + rg;
                int col = (wn * 2 + tn) * 16 + l15;
                unsigned pr = f2bf(accr[tm][tn][rg]);
                unsigned pi = f2bf(acci[tm][tn][rg]);
                Y[row * Y_STRIDE + col] = pr | (pi << 16);
            }

    __syncthreads();

    // ---- epilogue: y[128q+m] = sum_r tw(r*m)*Y[b8+r][m] * e^{i 2pi r q/8}
    // thread t: bl = t>>6, m in {2*(t&63), +1}; both halves read as one b64.
    const int m0 = t & 63;
    const int bl = t >> 6;

    uint2 zpk[8];
#pragma unroll
    for (int r = 0; r < 8; ++r)
        zpk[r] = *(const uint2*)(Y + (bl * 8 + r) * Y_STRIDE + 2 * m0);

    float u_re[2][8], u_im[2][8];

#pragma unroll
    for (int half = 0; half < 2; ++half) {
        int m = 2 * m0 + half;
        // twiddles tw_r = e^{i 2pi r m/1024}, r=0..7: one sincos + product ladder
        float cr[8], sr[8];
        cr[0] = 1.0f; sr[0] = 0.0f;
        __sincosf((float)m * 6.135923151542565e-3f, &sr[1], &cr[1]);
#pragma unroll
        for (int r = 2; r < 8; ++r) {
            int ha = r >> 1, hb = r - ha;     // depth<=3 chained muls, err ~1e-6
            cr[r] = cr[ha] * cr[hb] - sr[ha] * sr[hb];
            sr[r] = cr[ha] * sr[hb] + sr[ha] * cr[hb];
        }
        float zr[8], zi[8];
#pragma unroll
        for (int r = 0; r < 8; ++r) {
            unsigned pk = half ? zpk[r].y : zpk[r].x;
            float yre = bf2f(pk & 0xffffu);
            float yim = bf2f(pk >> 16);
            zr[r] = cr[r] * yre - sr[r] * yim;
            zi[r] = cr[r] * yim + sr[r] * yre;
        }
        // evens (z0,z2,z4,z6) -> 4-pt inverse DFT
        float t0r = zr[0] + zr[4], t0i = zi[0] + zi[4];
        float t1r = zr[0] - zr[4], t1i = zi[0] - zi[4];
        float t2r = zr[2] + zr[6], t2i = zi[2] + zi[6];
        float t3r = zr[2] - zr[6], t3i = zi[2] - zi[6];
        float E0r = t0r + t2r, E0i = t0i + t2i;
        float E2r = t0r - t2r, E2i = t0i - t2i;
        float E1r = t1r - t3i, E1i = t1i + t3r;    // t1 + i*t3
        float E3r = t1r + t3i, E3i = t1i - t3r;    // t1 - i*t3
        // odds (z1,z3,z5,z7)
        float s0r = zr[1] + zr[5], s0i = zi[1] + zi[5];
        float s1r = zr[1] - zr[5], s1i = zi[1] - zi[5];
        float s2r = zr[3] + zr[7], s2i = zi[3] + zi[7];
        float s3r = zr[3] - zr[7], s3i = zi[3] - zi[7];
        float O0r = s0r + s2r, O0i = s0i + s2i;
        float O2r = s0r - s2r, O2i = s0i - s2i;
        float O1r = s1r - s3i, O1i = s1i + s3r;
        float O3r = s1r + s3i, O3i = s1i - s3r;
        const float C8 = 0.70710678118654752f;
        float p0r = O0r,                  p0i = O0i;                  // w^0
        float p1r = C8 * (O1r - O1i),     p1i = C8 * (O1r + O1i);     // w^1 = c+ic
        float p2r = -O2i,                 p2i = O2r;                  // w^2 = i
        float p3r = -C8 * (O3r + O3i),    p3i = C8 * (O3r - O3i);     // w^3 = -c+ic
        u_re[half][0] = E0r + p0r; u_im[half][0] = E0i + p0i;
        u_re[half][1] = E1r + p1r; u_im[half][1] = E1i + p1i;
        u_re[half][2] = E2r + p2r; u_im[half][2] = E2i + p2i;
        u_re[half][3] = E3r + p3r; u_im[half][3] = E3i + p3i;
        u_re[half][4] = E0r - p0r; u_im[half][4] = E0i - p0i;
        u_re[half][5] = E1r - p1r; u_im[half][5] = E1i - p1i;
        u_re[half][6] = E2r - p2r; u_im[half][6] = E2i - p2i;
        u_re[half][7] = E3r - p3r; u_im[half][7] = E3i - p3i;
    }

    {
        size_t bg = (size_t)(blk * TB + bl);
        float* outre = out + bg * NFFT + 2 * m0;
        float* outim = out + (size_t)BATCH_N * NFFT + bg * NFFT + 2 * m0;
#pragma unroll
        for (int q = 0; q < 8; ++q) {
            *(float2*)(outre + q * 128) = make_float2(u_re[0][q], u_re[1][q]);
            *(float2*)(outim + q * 128) = make_float2(u_im[0][q], u_im[1][q]);
        }
    }
}

extern "C" void kernel_launch(void* const* d_in, const int* in_sizes, int n_in,
                              void* d_out, int out_size, void* d_ws, size_t ws_size,
                              hipStream_t stream) {
    const float* re  = (const float*)d_in[0];
    const float* im  = (const float*)d_in[1];
    unsigned short* wbf = (unsigned short*)d_ws;   // 64 KB: Wr | Wi bf16

    prep_w<<<16, 256, 0, stream>>>((const float*)d_in[2], (const float*)d_in[3],
                                   (const float*)d_in[4], (const float*)d_in[5], wbf);
    ifft_fused<<<GRID_N, NTHREADS, 0, stream>>>(re, im, wbf, (float*)d_out);
}